// Round 6
// baseline (338.816 us; speedup 1.0000x reference)
//
#include <hip/hip_runtime.h>

#define KK 64
#define TT 1024
#define BB 256
#define START_TAG 0

__device__ __forceinline__ float lane_bcast(float v, int lane) {
    return __int_as_float(__builtin_amdgcn_readlane(__float_as_int(v), lane));
}

// gfx950 two-register half-wave / row-pair swaps. VALU lane-crossing ops
// (v_permlane*_swap_b32) — NOT DS: ~4-8 cyc latency vs ~130 cyc LDS round
// trip. Both operands are read-write (the two registers exchange lanes).
#define SWAPL32(X, Y) asm("v_permlane32_swap_b32 %0, %1" : "+v"(X), "+v"(Y));
#define SWAPL16(X, Y) asm("v_permlane16_swap_b32 %0, %1" : "+v"(X), "+v"(Y));

// DPP row-rotate (within each 16-lane row) applied to src0 of mov/fmac:
// delivers one rotated neighbor value per instruction, zero extra gathers.
#define RMOVI(D, S, K) \
    asm("v_mov_b32 %0, %1 row_ror:" #K " row_mask:0xf bank_mask:0xf" \
        : "=v"(D) : "v"(S));
#define RFMA(D, S, K, E) \
    asm("v_fmac_f32 %0, %1, %2 row_ror:" #K " row_mask:0xf bank_mask:0xf" \
        : "+v"(D) : "v"(S), "v"(E));

// Direction/semantics-proof et gather: the SAME permlane+row_ror network is
// run on the lane-id vector at setup; et is gathered at the resulting
// per-lane indices, so every MAC multiplies the matching trans entry no
// matter which exact lane-mapping convention the HW implements.
#define GATHER(dst, src, K) { int x_; RMOVI(x_, src, K) dst = __expf(trow[x_]); }

#define PIN4(p,q,r,s) asm volatile("" : "+v"(p), "+v"(q), "+v"(r), "+v"(s));

// One rotation level: 4 DPP fmacs, one per block-register chain (dep
// distance 4 between same-chain ops -> 4-way ILP).
#define FMAROW(K) \
    RFMA(c0, U,  K, etA##K) RFMA(c1, U2, K, etB##K) \
    RFMA(c2, V,  K, etC##K) RFMA(c3, V2, K, etD##K)

// One recurrence step — ~81 instructions, ZERO DS operations:
//  4 v_mov + 1 permlane32_swap + 2 permlane16_swap build P-registers
//  {U,U2,V,V2} that per 16-row jointly hold all four 16-state blocks of a
//  (coverage holds under any two-register-swap semantics: the network
//   always partitions the 4 blocks per row; verified via absmax harness)
//  64 MACs via row_ror DPP fmac on 4 independent chains
//  tree + scale + mask select (+ renorm every 4th step)
// s_nop fences: VALU-write -> lane-crossing-read hazards around inline asm
// are the programmer's responsibility (compiler only guards its own code).
#define DO_STEP(EFV, MKV, RN) { \
    float U = a, V = a; \
    asm volatile("s_nop 1" : "+v"(U), "+v"(V)); \
    SWAPL32(U, V) \
    float U2 = U, V2 = V; \
    asm volatile("s_nop 1" : "+v"(U), "+v"(U2), "+v"(V), "+v"(V2)); \
    SWAPL16(U, U2) \
    SWAPL16(V, V2) \
    asm volatile("s_nop 1" : "+v"(U), "+v"(U2), "+v"(V), "+v"(V2)); \
    float c0 = U * etA0, c1 = U2 * etB0, c2 = V * etC0, c3 = V2 * etD0; \
    FMAROW(1)  FMAROW(2)  FMAROW(3)  FMAROW(4)  FMAROW(5) \
    FMAROW(6)  FMAROW(7)  FMAROW(8)  FMAROW(9)  FMAROW(10) \
    FMAROW(11) FMAROW(12) FMAROW(13) FMAROW(14) FMAROW(15) \
    float s_ = (c0 + c1) + (c2 + c3); \
    float anew = s_ * (EFV); \
    a = ((MKV) != 0.0f) ? anew : a; \
    if (RN) { \
        float a1 = fmaxf(lane_bcast(a, 1), 1e-37f); \
        a *= __builtin_amdgcn_rcpf(a1); \
        offset += __logf(a1); \
    } \
}

// Forward algorithm in the probability domain. One wave per batch element;
// lane i owns state i. Rounds 0-5 showed the recurrence is bound by
// single-wave issue cadence + exposed DS latency; this version removes the
// DS pipe from the loop entirely (permlane swaps + DPP rotations, all VALU).
// Renorm once per 4 steps by a[1] (wave-uniform positive scale is exact via
// offset += log(scale)).
__global__ __launch_bounds__(64)
__attribute__((amdgpu_waves_per_eu(1, 1)))
void crf_forward_kernel(
    const float* __restrict__ feats,
    const float* __restrict__ trans,
    const float* __restrict__ masks,
    const int*   __restrict__ tags,
    float* __restrict__ out)
{
    const int b = blockIdx.x;
    const int i = threadIdx.x;

    const float* trow = trans + i * KK;

    // --- run the permutation network on lane ids (index vectors) ---
    int lid = i;
    asm volatile("s_nop 1" : "+v"(lid));
    int jU = lid, jV = lid;
    asm volatile("s_nop 1" : "+v"(jU), "+v"(jV));
    SWAPL32(jU, jV)
    int jU2 = jU, jV2 = jV;
    asm volatile("s_nop 1" : "+v"(jU), "+v"(jU2), "+v"(jV), "+v"(jV2));
    SWAPL16(jU, jU2)
    SWAPL16(jV, jV2)
    asm volatile("s_nop 1" : "+v"(jU), "+v"(jU2), "+v"(jV), "+v"(jV2));

    // --- gather et[chain][rot] = exp(trans[i][sigma_chain(ror_rot(i))]) ---
    float etA0, etA1, etA2, etA3, etA4, etA5, etA6, etA7,
          etA8, etA9, etA10, etA11, etA12, etA13, etA14, etA15;
    float etB0, etB1, etB2, etB3, etB4, etB5, etB6, etB7,
          etB8, etB9, etB10, etB11, etB12, etB13, etB14, etB15;
    float etC0, etC1, etC2, etC3, etC4, etC5, etC6, etC7,
          etC8, etC9, etC10, etC11, etC12, etC13, etC14, etC15;
    float etD0, etD1, etD2, etD3, etD4, etD5, etD6, etD7,
          etD8, etD9, etD10, etD11, etD12, etD13, etD14, etD15;
    etA0 = __expf(trow[jU]);  etB0 = __expf(trow[jU2]);
    etC0 = __expf(trow[jV]);  etD0 = __expf(trow[jV2]);
    GATHER(etA1, jU, 1)   GATHER(etA2, jU, 2)   GATHER(etA3, jU, 3)
    GATHER(etA4, jU, 4)   GATHER(etA5, jU, 5)   GATHER(etA6, jU, 6)
    GATHER(etA7, jU, 7)   GATHER(etA8, jU, 8)   GATHER(etA9, jU, 9)
    GATHER(etA10, jU, 10) GATHER(etA11, jU, 11) GATHER(etA12, jU, 12)
    GATHER(etA13, jU, 13) GATHER(etA14, jU, 14) GATHER(etA15, jU, 15)
    GATHER(etB1, jU2, 1)   GATHER(etB2, jU2, 2)   GATHER(etB3, jU2, 3)
    GATHER(etB4, jU2, 4)   GATHER(etB5, jU2, 5)   GATHER(etB6, jU2, 6)
    GATHER(etB7, jU2, 7)   GATHER(etB8, jU2, 8)   GATHER(etB9, jU2, 9)
    GATHER(etB10, jU2, 10) GATHER(etB11, jU2, 11) GATHER(etB12, jU2, 12)
    GATHER(etB13, jU2, 13) GATHER(etB14, jU2, 14) GATHER(etB15, jU2, 15)
    GATHER(etC1, jV, 1)   GATHER(etC2, jV, 2)   GATHER(etC3, jV, 3)
    GATHER(etC4, jV, 4)   GATHER(etC5, jV, 5)   GATHER(etC6, jV, 6)
    GATHER(etC7, jV, 7)   GATHER(etC8, jV, 8)   GATHER(etC9, jV, 9)
    GATHER(etC10, jV, 10) GATHER(etC11, jV, 11) GATHER(etC12, jV, 12)
    GATHER(etC13, jV, 13) GATHER(etC14, jV, 14) GATHER(etC15, jV, 15)
    GATHER(etD1, jV2, 1)   GATHER(etD2, jV2, 2)   GATHER(etD3, jV2, 3)
    GATHER(etD4, jV2, 4)   GATHER(etD5, jV2, 5)   GATHER(etD6, jV2, 6)
    GATHER(etD7, jV2, 7)   GATHER(etD8, jV2, 8)   GATHER(etD9, jV2, 9)
    GATHER(etD10, jV2, 10) GATHER(etD11, jV2, 11) GATHER(etD12, jV2, 12)
    GATHER(etD13, jV2, 13) GATHER(etD14, jV2, 14) GATHER(etD15, jV2, 15)

    PIN4(etA0, etA1, etA2, etA3)     PIN4(etA4, etA5, etA6, etA7)
    PIN4(etA8, etA9, etA10, etA11)   PIN4(etA12, etA13, etA14, etA15)
    PIN4(etB0, etB1, etB2, etB3)     PIN4(etB4, etB5, etB6, etB7)
    PIN4(etB8, etB9, etB10, etB11)   PIN4(etB12, etB13, etB14, etB15)
    PIN4(etC0, etC1, etC2, etC3)     PIN4(etC4, etC5, etC6, etC7)
    PIN4(etC8, etC9, etC10, etC11)   PIN4(etC12, etC13, etC14, etC15)
    PIN4(etD0, etD1, etD2, etD3)     PIN4(etD4, etD5, etD6, etD7)
    PIN4(etD8, etD9, etD10, etD11)   PIN4(etD12, etD13, etD14, etD15)

    float a = (i == START_TAG) ? 1.0f : 0.0f;  // exp(alpha0)
    float offset = 0.0f;                        // running log-scale

    const float* fb = feats + (size_t)b * TT * KK;
    const float* mb = masks + (size_t)b * TT;

    // prologue prefetch: steps t = 1..4
    float cf0 = fb[1 * KK + i], cf1 = fb[2 * KK + i];
    float cf2 = fb[3 * KK + i], cf3 = fb[4 * KK + i];
    float cm0 = mb[1], cm1 = mb[2], cm2 = mb[3], cm3 = mb[4];

    // groups t0 = 1,5,...,1021; last group's 4th step (t=1024) masked off
    for (int t0 = 1; t0 < TT; t0 += 4) {
        int p0 = (t0 + 4 < TT) ? t0 + 4 : TT - 1;
        int p1 = (t0 + 5 < TT) ? t0 + 5 : TT - 1;
        int p2 = (t0 + 6 < TT) ? t0 + 6 : TT - 1;
        int p3 = (t0 + 7 < TT) ? t0 + 7 : TT - 1;
        float nf0 = fb[p0 * KK + i], nf1 = fb[p1 * KK + i];
        float nf2 = fb[p2 * KK + i], nf3 = fb[p3 * KK + i];
        float nm0 = mb[p0], nm1 = mb[p1], nm2 = mb[p2], nm3 = mb[p3];

        // exp(feat): inputs prefetched a full group ago -> off critical path
        float ef0 = __expf(cf0), ef1 = __expf(cf1);
        float ef2 = __expf(cf2), ef3 = __expf(cf3);

        DO_STEP(ef0, cm0, 0)
        DO_STEP(ef1, cm1, 0)
        DO_STEP(ef2, cm2, 0)
        float m3 = (t0 + 3 < TT) ? cm3 : 0.0f;   // only last group clips
        DO_STEP(ef3, m3, 1)                       // renorm folded into step 4

        cf0 = nf0; cf1 = nf1; cf2 = nf2; cf3 = nf3;
        cm0 = nm0; cm1 = nm1; cm2 = nm2; cm3 = nm3;
    }

    // forward_score = offset + log(sum_j a_j)
    float s = a;
    #pragma unroll
    for (int off = 32; off >= 1; off >>= 1)
        s += __shfl_xor(s, off, 64);
    float fwd_score = offset + __logf(s);

    // ---- fused gold score: sum_t (trans[ct,pt] + feats[t,ct]) * mask[t] ----
    const int* tg = tags + b * TT;
    float g = 0.f;
    for (int t = 1 + i; t < TT; t += 64) {
        int ct = tg[t], pt = tg[t - 1];
        g += (trans[ct * KK + pt] + fb[t * KK + ct]) * mb[t];
    }
    #pragma unroll
    for (int off = 32; off >= 1; off >>= 1)
        g += __shfl_xor(g, off, 64);

    if (i == 0) atomicAdd(out, (fwd_score - g) * (1.0f / (float)BB));
}

extern "C" void kernel_launch(void* const* d_in, const int* in_sizes, int n_in,
                              void* d_out, int out_size, void* d_ws, size_t ws_size,
                              hipStream_t stream) {
    const float* feats = (const float*)d_in[0];
    const float* trans = (const float*)d_in[1];
    const int*   tags  = (const int*)d_in[2];
    const float* masks = (const float*)d_in[3];
    float* out = (float*)d_out;

    hipMemsetAsync(out, 0, sizeof(float), stream);  // atomicAdd accumulator
    crf_forward_kernel<<<BB, 64, 0, stream>>>(feats, trans, masks, tags, out);
}

// Round 7
// 305.276 us; speedup vs baseline: 1.1099x; 1.1099x over previous
//
#include <hip/hip_runtime.h>

#define KK 64
#define TT 1024
#define BB 256
#define START_TAG 0

typedef float v2f __attribute__((ext_vector_type(2)));
typedef float v4f __attribute__((ext_vector_type(4)));

__device__ __forceinline__ float lane_bcast(float v, int lane) {
    return __int_as_float(__builtin_amdgcn_readlane(__float_as_int(v), lane));
}

// Packed dual-fp32 VALU (VOP3P), register-only non-volatile asm.
#define PKMUL(D, S, E) asm("v_pk_mul_f32 %0, %1, %2"     : "=v"(D) : "v"(S), "v"(E));
#define PKFMA(D, S, E) asm("v_pk_fma_f32 %0, %1, %2, %0" : "+v"(D) : "v"(S), "v"(E));
#define PKADD(D, X, Y) asm("v_pk_add_f32 %0, %1, %2"     : "=v"(D) : "v"(X), "v"(Y));

// v4f halves as v2f (sub-register aliasing, no movs).
#define LOV(W) (__builtin_shufflevector((W), (W), 0, 1))
#define HIV(W) (__builtin_shufflevector((W), (W), 2, 3))

// DPP row-rotate on src0 of mov/fmac (16-lane row). Direction-proof: setup
// runs the SAME dpp control on the lane-id vector and gathers exp(trans) at
// the resulting indices (r5-verified, absmax 0.0). Only 16 DPP fmacs/step —
// r6 showed heavy DPP (64/step) runs at ~8 cyc/inst; 16 is the proven scale.
#define RMOVI(D, S, K) \
    asm("v_mov_b32 %0, %1 row_ror:" #K " row_mask:0xf bank_mask:0xf" \
        : "=v"(D) : "v"(S));
#define RORMUL(D, K, E) \
    asm("v_mul_f32 %0, %1, %2 row_ror:" #K " row_mask:0xf bank_mask:0xf" \
        : "=v"(D) : "v"(a), "v"(E));
#define RORFMA(D, K, E) \
    asm("v_fmac_f32 %0, %1, %2 row_ror:" #K " row_mask:0xf bank_mask:0xf" \
        : "+v"(D) : "v"(a), "v"(E));

#define PIN4(p,q,r,s) asm volatile("" : "+v"(p), "+v"(q), "+v"(r), "+v"(s));

// One recurrence step with MANUALLY COUNTED lgkmcnt overlap:
//   ds_write_b32 + 12x ds_read_b128 issued back-to-back (volatile asm, in
//   program order; DS ops of one wave execute and retire IN ORDER, so the
//   write is visible to the reads with no wait, and lgkmcnt counts retire
//   order exactly: 13 issued -> lgkmcnt(8) == write+A-block done).
//   16 own-row DPP fmacs fill the ~170cy write->first-return shadow.
//   Consumption (asm pk) is released block-by-block: lgkmcnt(8)/(4)/(0),
//   each wait followed by sched_barrier(0) -- rule #18: hipcc hoists
//   register-only asm past inline-asm waitcnt despite data flow.
// No other lgkm traffic in the loop (prefetch = global_load -> vmcnt only).
#define DO_STEP(EFV, MKV, RN) { \
    asm volatile("ds_write_b32 %0, %1" :: "v"(adW), "v"(a)); \
    v4f wA0, wA1, wA2, wA3, wB0, wB1, wB2, wB3, wC0, wC1, wC2, wC3; \
    asm volatile("ds_read_b128 %0, %1"           : "=v"(wA0) : "v"(adA)); \
    asm volatile("ds_read_b128 %0, %1 offset:16" : "=v"(wA1) : "v"(adA)); \
    asm volatile("ds_read_b128 %0, %1 offset:32" : "=v"(wA2) : "v"(adA)); \
    asm volatile("ds_read_b128 %0, %1 offset:48" : "=v"(wA3) : "v"(adA)); \
    asm volatile("ds_read_b128 %0, %1"           : "=v"(wB0) : "v"(adB)); \
    asm volatile("ds_read_b128 %0, %1 offset:16" : "=v"(wB1) : "v"(adB)); \
    asm volatile("ds_read_b128 %0, %1 offset:32" : "=v"(wB2) : "v"(adB)); \
    asm volatile("ds_read_b128 %0, %1 offset:48" : "=v"(wB3) : "v"(adB)); \
    asm volatile("ds_read_b128 %0, %1"           : "=v"(wC0) : "v"(adC)); \
    asm volatile("ds_read_b128 %0, %1 offset:16" : "=v"(wC1) : "v"(adC)); \
    asm volatile("ds_read_b128 %0, %1 offset:32" : "=v"(wC2) : "v"(adC)); \
    asm volatile("ds_read_b128 %0, %1 offset:48" : "=v"(wC3) : "v"(adC)); \
    float sA = a * er0; \
    float sB; RORMUL(sB, 1, er1) \
    RORFMA(sA, 2,  er2)  RORFMA(sB, 3,  er3) \
    RORFMA(sA, 4,  er4)  RORFMA(sB, 5,  er5) \
    RORFMA(sA, 6,  er6)  RORFMA(sB, 7,  er7) \
    RORFMA(sA, 8,  er8)  RORFMA(sB, 9,  er9) \
    RORFMA(sA, 10, er10) RORFMA(sB, 11, er11) \
    RORFMA(sA, 12, er12) RORFMA(sB, 13, er13) \
    RORFMA(sA, 14, er14) RORFMA(sB, 15, er15) \
    asm volatile("s_waitcnt lgkmcnt(8)" ::: "memory"); \
    __builtin_amdgcn_sched_barrier(0); \
    v2f q0, q1, q2, q3; \
    PKMUL(q0, LOV(wA0), eA0) PKMUL(q1, HIV(wA0), eA1) \
    PKMUL(q2, LOV(wA1), eA2) PKMUL(q3, HIV(wA1), eA3) \
    PKFMA(q0, LOV(wA2), eA4) PKFMA(q1, HIV(wA2), eA5) \
    PKFMA(q2, LOV(wA3), eA6) PKFMA(q3, HIV(wA3), eA7) \
    asm volatile("s_waitcnt lgkmcnt(4)" ::: "memory"); \
    __builtin_amdgcn_sched_barrier(0); \
    PKFMA(q0, LOV(wB0), eB0) PKFMA(q1, HIV(wB0), eB1) \
    PKFMA(q2, LOV(wB1), eB2) PKFMA(q3, HIV(wB1), eB3) \
    PKFMA(q0, LOV(wB2), eB4) PKFMA(q1, HIV(wB2), eB5) \
    PKFMA(q2, LOV(wB3), eB6) PKFMA(q3, HIV(wB3), eB7) \
    asm volatile("s_waitcnt lgkmcnt(0)" ::: "memory"); \
    __builtin_amdgcn_sched_barrier(0); \
    PKFMA(q0, LOV(wC0), eC0) PKFMA(q1, HIV(wC0), eC1) \
    PKFMA(q2, LOV(wC1), eC2) PKFMA(q3, HIV(wC1), eC3) \
    PKFMA(q0, LOV(wC2), eC4) PKFMA(q1, HIV(wC2), eC5) \
    PKFMA(q2, LOV(wC3), eC6) PKFMA(q3, HIV(wC3), eC7) \
    v2f qA, qB, qC; \
    PKADD(qA, q0, q1) PKADD(qB, q2, q3) PKADD(qC, qA, qB) \
    float s_ = (qC.x + qC.y) + (sA + sB); \
    float anew = s_ * (EFV); \
    a = ((MKV) != 0.0f) ? anew : a; \
    if (RN) { \
        float a1 = fmaxf(lane_bcast(a, 1), 1e-37f); \
        a *= __builtin_amdgcn_rcpf(a1); \
        offset += __logf(a1); \
    } \
    asm volatile("s_nop 1" : "+v"(a)); /* VALU-write -> DPP-read fence */ \
}

// Forward algorithm in the probability domain. One wave per batch element;
// lane i owns state i. Per-step model from rounds 0-6:
//   cyc ~= write(40) + first-LDS-return(170) + stream + post-wait-VALU*4.5
// This version overlaps consumption with the in-flight read stream via
// counted lgkmcnt and fills the first-return shadow with own-row DPP fmacs.
// Renorm once per 4 steps by a[1] (wave-uniform positive scale is exact via
// offset += log(scale)).
__global__ __launch_bounds__(64)
__attribute__((amdgpu_waves_per_eu(1, 1)))
void crf_forward_kernel(
    const float* __restrict__ feats,
    const float* __restrict__ trans,
    const float* __restrict__ masks,
    const int*   __restrict__ tags,
    float* __restrict__ out)
{
    const int b = blockIdx.x;
    const int i = threadIdx.x;
    const int r = (i >> 4) & 3;        // 16-lane row id
    const int rowbase = i & 48;        // first state of own row

    __shared__ __align__(16) float abuf[KK];

    const float* trow = trans + i * KK;

    // --- own-row et in HW rotate order (direction-proof construction) ---
    int lid = i & 15;
    asm volatile("s_nop 1" : "+v"(lid));   // VALU-write -> DPP-read guard
    int x1, x2, x3, x4, x5, x6, x7, x8, x9, x10, x11, x12, x13, x14, x15;
    RMOVI(x1, lid, 1)   RMOVI(x2, lid, 2)   RMOVI(x3, lid, 3)   RMOVI(x4, lid, 4)
    RMOVI(x5, lid, 5)   RMOVI(x6, lid, 6)   RMOVI(x7, lid, 7)   RMOVI(x8, lid, 8)
    RMOVI(x9, lid, 9)   RMOVI(x10, lid, 10) RMOVI(x11, lid, 11) RMOVI(x12, lid, 12)
    RMOVI(x13, lid, 13) RMOVI(x14, lid, 14) RMOVI(x15, lid, 15)
    float er0  = __expf(trow[rowbase + lid]);
    float er1  = __expf(trow[rowbase + x1]),  er2  = __expf(trow[rowbase + x2]);
    float er3  = __expf(trow[rowbase + x3]),  er4  = __expf(trow[rowbase + x4]);
    float er5  = __expf(trow[rowbase + x5]),  er6  = __expf(trow[rowbase + x6]);
    float er7  = __expf(trow[rowbase + x7]),  er8  = __expf(trow[rowbase + x8]);
    float er9  = __expf(trow[rowbase + x9]),  er10 = __expf(trow[rowbase + x10]);
    float er11 = __expf(trow[rowbase + x11]), er12 = __expf(trow[rowbase + x12]);
    float er13 = __expf(trow[rowbase + x13]), er14 = __expf(trow[rowbase + x14]);
    float er15 = __expf(trow[rowbase + x15]);

    // --- other-rows et pairs, chunk order (r+1, r+2, r+3) mod 4 ---
    const int cb1 = ((r + 1) & 3) << 4;   // float index of chunk base
    const int cb2 = ((r + 2) & 3) << 4;
    const int cb3 = ((r + 3) & 3) << 4;
#define DECLE(nm, cb, p) v2f nm = { __expf(trow[(cb) + 2*(p)]), __expf(trow[(cb) + 2*(p) + 1]) };
    DECLE(eA0, cb1, 0) DECLE(eA1, cb1, 1) DECLE(eA2, cb1, 2) DECLE(eA3, cb1, 3)
    DECLE(eA4, cb1, 4) DECLE(eA5, cb1, 5) DECLE(eA6, cb1, 6) DECLE(eA7, cb1, 7)
    DECLE(eB0, cb2, 0) DECLE(eB1, cb2, 1) DECLE(eB2, cb2, 2) DECLE(eB3, cb2, 3)
    DECLE(eB4, cb2, 4) DECLE(eB5, cb2, 5) DECLE(eB6, cb2, 6) DECLE(eB7, cb2, 7)
    DECLE(eC0, cb3, 0) DECLE(eC1, cb3, 1) DECLE(eC2, cb3, 2) DECLE(eC3, cb3, 3)
    DECLE(eC4, cb3, 4) DECLE(eC5, cb3, 5) DECLE(eC6, cb3, 6) DECLE(eC7, cb3, 7)

    PIN4(er0, er1, er2, er3)   PIN4(er4, er5, er6, er7)
    PIN4(er8, er9, er10, er11) PIN4(er12, er13, er14, er15)
    PIN4(eA0, eA1, eA2, eA3)   PIN4(eA4, eA5, eA6, eA7)
    PIN4(eB0, eB1, eB2, eB3)   PIN4(eB4, eB5, eB6, eB7)
    PIN4(eC0, eC1, eC2, eC3)   PIN4(eC4, eC5, eC6, eC7)

    // DS byte addresses (generic LDS pointer low 32 bits = DS offset).
    unsigned lds_base = (unsigned)(uintptr_t)(void*)abuf;
    unsigned adW = lds_base + ((unsigned)i << 2);
    unsigned adA = lds_base + ((unsigned)cb1 << 2);
    unsigned adB = lds_base + ((unsigned)cb2 << 2);
    unsigned adC = lds_base + ((unsigned)cb3 << 2);

    float a = (i == START_TAG) ? 1.0f : 0.0f;  // exp(alpha0)
    float offset = 0.0f;                        // running log-scale
    asm volatile("s_nop 1" : "+v"(a));          // guard before first DPP use

    const float* fb = feats + (size_t)b * TT * KK;
    const float* mb = masks + (size_t)b * TT;

    // prologue prefetch: steps t = 1..4
    float cf0 = fb[1 * KK + i], cf1 = fb[2 * KK + i];
    float cf2 = fb[3 * KK + i], cf3 = fb[4 * KK + i];
    float cm0 = mb[1], cm1 = mb[2], cm2 = mb[3], cm3 = mb[4];

    // groups t0 = 1,5,...,1021; last group's 4th step (t=1024) masked off
    for (int t0 = 1; t0 < TT; t0 += 4) {
        int p0 = (t0 + 4 < TT) ? t0 + 4 : TT - 1;
        int p1 = (t0 + 5 < TT) ? t0 + 5 : TT - 1;
        int p2 = (t0 + 6 < TT) ? t0 + 6 : TT - 1;
        int p3 = (t0 + 7 < TT) ? t0 + 7 : TT - 1;
        float nf0 = fb[p0 * KK + i], nf1 = fb[p1 * KK + i];
        float nf2 = fb[p2 * KK + i], nf3 = fb[p3 * KK + i];
        float nm0 = mb[p0], nm1 = mb[p1], nm2 = mb[p2], nm3 = mb[p3];

        // exp(feat): inputs prefetched a full group ago -> off critical path
        float ef0 = __expf(cf0), ef1 = __expf(cf1);
        float ef2 = __expf(cf2), ef3 = __expf(cf3);

        DO_STEP(ef0, cm0, 0)
        DO_STEP(ef1, cm1, 0)
        DO_STEP(ef2, cm2, 0)
        float m3 = (t0 + 3 < TT) ? cm3 : 0.0f;   // only last group clips
        DO_STEP(ef3, m3, 1)                       // renorm folded into step 4

        cf0 = nf0; cf1 = nf1; cf2 = nf2; cf3 = nf3;
        cm0 = nm0; cm1 = nm1; cm2 = nm2; cm3 = nm3;
    }

    // forward_score = offset + log(sum_j a_j)
    float s = a;
    #pragma unroll
    for (int off = 32; off >= 1; off >>= 1)
        s += __shfl_xor(s, off, 64);
    float fwd_score = offset + __logf(s);

    // ---- fused gold score: sum_t (trans[ct,pt] + feats[t,ct]) * mask[t] ----
    const int* tg = tags + b * TT;
    float g = 0.f;
    for (int t = 1 + i; t < TT; t += 64) {
        int ct = tg[t], pt = tg[t - 1];
        g += (trans[ct * KK + pt] + fb[t * KK + ct]) * mb[t];
    }
    #pragma unroll
    for (int off = 32; off >= 1; off >>= 1)
        g += __shfl_xor(g, off, 64);

    if (i == 0) atomicAdd(out, (fwd_score - g) * (1.0f / (float)BB));
}

extern "C" void kernel_launch(void* const* d_in, const int* in_sizes, int n_in,
                              void* d_out, int out_size, void* d_ws, size_t ws_size,
                              hipStream_t stream) {
    const float* feats = (const float*)d_in[0];
    const float* trans = (const float*)d_in[1];
    const int*   tags  = (const int*)d_in[2];
    const float* masks = (const float*)d_in[3];
    float* out = (float*)d_out;

    hipMemsetAsync(out, 0, sizeof(float), stream);  // atomicAdd accumulator
    crf_forward_kernel<<<BB, 64, 0, stream>>>(feats, trans, masks, tags, out);
}